// Round 1
// baseline (3218.253 us; speedup 1.0000x reference)
//
#include <hip/hip_runtime.h>
#include <cstdint>
#include <cstddef>

// Problem constants
// B=16, C=512, H=W=64, HW=4096, C8=64, C2=256, M(keys)=1024

static __device__ __forceinline__ float max4f(float a, float b, float c, float d) {
  return fmaxf(fmaxf(a, b), fmaxf(c, d));
}

// ---------------- pack weights: Wcat [384][512], bcat[384] ----------------
__global__ __launch_bounds__(256) void pack_kernel(
    const float* __restrict__ wt, const float* __restrict__ bt,
    const float* __restrict__ wp, const float* __restrict__ bp,
    const float* __restrict__ wg, const float* __restrict__ bg,
    float* __restrict__ Wcat, float* __restrict__ bcat) {
  int i = blockIdx.x * 256 + threadIdx.x;
  if (i < 384 * 512) {
    int o = i >> 9, k = i & 511;
    float v;
    if (o < 64)       v = wt[o * 512 + k];
    else if (o < 128) v = wp[(o - 64) * 512 + k];
    else              v = wg[(o - 128) * 512 + k];
    Wcat[i] = v;
  }
  if (i < 384) {
    float v;
    if (i < 64)       v = bt[i];
    else if (i < 128) v = bp[i - 64];
    else              v = bg[i - 128];
    bcat[i] = v;
  }
}

// ---------------- conv GEMM + fused maxpool epilogue ----------------
// Y[384,4096] = Wcat @ X_b ; theta rows -> theta buf, phi/g rows -> 2x2 pooled
// tile 128x128, 256 threads, 8x8 acc per thread.
// N-tile of 128 aligned == image rows (2*nt, 2*nt+1) -> pool is block-local.
__global__ __launch_bounds__(256) void conv_pool_kernel(
    const float* __restrict__ X, const float* __restrict__ Wcat,
    const float* __restrict__ bcat,
    float* __restrict__ theta, float* __restrict__ phi_p, float* __restrict__ g_p) {
  const int b = blockIdx.z, mt = blockIdx.y, nt = blockIdx.x;
  const int m0 = mt * 128, n0 = nt * 128;
  __shared__ union {
    struct { float As[16][132]; float Bs[16][132]; } ab;
    float cs[64][132];
  } sm;
  const int t = threadIdx.x, tx = t & 15, ty = t >> 4;
  float acc[8][8];
#pragma unroll
  for (int i = 0; i < 8; ++i)
#pragma unroll
    for (int j = 0; j < 8; ++j) acc[i][j] = 0.f;
  const float* Xb = X + (size_t)b * 512 * 4096;

  for (int k0 = 0; k0 < 512; k0 += 16) {
#pragma unroll
    for (int p = 0; p < 2; ++p) {  // A tile (transposed store)
      int e = p * 256 + t;
      int row = e >> 2, kq = e & 3;
      float4 a4 = *(const float4*)&Wcat[(size_t)(m0 + row) * 512 + k0 + kq * 4];
      sm.ab.As[kq * 4 + 0][row] = a4.x;
      sm.ab.As[kq * 4 + 1][row] = a4.y;
      sm.ab.As[kq * 4 + 2][row] = a4.z;
      sm.ab.As[kq * 4 + 3][row] = a4.w;
    }
#pragma unroll
    for (int p = 0; p < 2; ++p) {  // B tile (direct)
      int e = p * 256 + t;
      int kr = e >> 5, nq = e & 31;
      *(float4*)&sm.ab.Bs[kr][nq * 4] =
          *(const float4*)&Xb[(size_t)(k0 + kr) * 4096 + n0 + nq * 4];
    }
    __syncthreads();
#pragma unroll
    for (int kk = 0; kk < 16; ++kk) {
      float4 a0 = *(const float4*)&sm.ab.As[kk][ty * 8];
      float4 a1 = *(const float4*)&sm.ab.As[kk][ty * 8 + 4];
      float4 b0 = *(const float4*)&sm.ab.Bs[kk][tx * 4];
      float4 b1 = *(const float4*)&sm.ab.Bs[kk][tx * 4 + 64];
      float av[8] = {a0.x, a0.y, a0.z, a0.w, a1.x, a1.y, a1.z, a1.w};
      float bv[8] = {b0.x, b0.y, b0.z, b0.w, b1.x, b1.y, b1.z, b1.w};
#pragma unroll
      for (int i = 0; i < 8; ++i)
#pragma unroll
        for (int j = 0; j < 8; ++j) acc[i][j] += av[i] * bv[j];
    }
    __syncthreads();
  }

  // epilogue in two stripes of 64 rows, via LDS C-tile
  for (int s = 0; s < 2; ++s) {
    if ((ty >> 3) == s) {
      int tyl = ty & 7;
#pragma unroll
      for (int i = 0; i < 8; ++i) {
        int r = tyl * 8 + i;
        float bias = bcat[m0 + s * 64 + r];
#pragma unroll
        for (int j = 0; j < 4; ++j) {
          sm.cs[r][tx * 4 + j]      = acc[i][j]     + bias;
          sm.cs[r][64 + tx * 4 + j] = acc[i][j + 4] + bias;
        }
      }
    }
    __syncthreads();
    const int o0 = m0 + s * 64;
    if (o0 < 64) {  // theta channels: straight copy
      int r = t >> 2, c0 = (t & 3) * 32;
      float* dst = theta + ((size_t)b * 64 + (o0 + r)) * 4096 + n0 + c0;
#pragma unroll
      for (int jj = 0; jj < 8; ++jj)
        *(float4*)&dst[jj * 4] = *(const float4*)&sm.cs[r][c0 + jj * 4];
    } else if (o0 < 128) {  // phi channels: 2x2 pool -> [B,64,1024]
      int r = t >> 2, px0 = (t & 3) * 8;
      float* dst = phi_p + ((size_t)b * 64 + (o0 - 64 + r)) * 1024 + nt * 32;
#pragma unroll
      for (int pp = 0; pp < 8; ++pp) {
        int px = px0 + pp;
        dst[px] = max4f(sm.cs[r][2 * px], sm.cs[r][2 * px + 1],
                        sm.cs[r][64 + 2 * px], sm.cs[r][64 + 2 * px + 1]);
      }
    } else {  // g channels: 2x2 pool -> transposed [B,1024,256]
      int ch = t & 63, px0 = (t >> 6) * 8;
      int gc = o0 - 128 + ch;
#pragma unroll
      for (int pp = 0; pp < 8; ++pp) {
        int px = px0 + pp;
        g_p[((size_t)b * 1024 + nt * 32 + px) * 256 + gc] =
            max4f(sm.cs[ch][2 * px], sm.cs[ch][2 * px + 1],
                  sm.cs[ch][64 + 2 * px], sm.cs[ch][64 + 2 * px + 1]);
      }
    }
    __syncthreads();
  }
}

// ---------------- fused attention: S = theta^T phi, softmax, O = S g ----------------
// block: 512 threads, 32 queries; S tile [32][1028] fp32 in LDS.
__global__ __launch_bounds__(512) void attn_kernel(
    const float* __restrict__ theta, const float* __restrict__ phi,
    const float* __restrict__ g, float* __restrict__ O) {
  const int b = blockIdx.y, qt = blockIdx.x, q0 = qt * 32;
  __shared__ float th_s[64][32];
  __shared__ float phi_s[64][64];
  __shared__ float S_s[32][1028];
  const int t = threadIdx.x;

  {  // load theta tile [64c x 32q]
    int c = t >> 3, qq = (t & 7) * 4;
    const float* p = theta + ((size_t)b * 64 + c) * 4096 + q0 + qq;
    *(float4*)&th_s[c][qq] = *(const float4*)p;
  }
  __syncthreads();

  const int qA = t >> 4;        // QK/softmax query (0..31), 16 threads per row
  const int l16 = t & 15;
  float th[64];
#pragma unroll
  for (int c = 0; c < 64; ++c) th[c] = th_s[c][qA];

  // ---- QK^T into S_s ----
  for (int mc = 0; mc < 16; ++mc) {
    __syncthreads();
    {  // load phi chunk [64c x 64m]
      int c = t >> 3, mm = (t & 7) * 8;
      const float* p = phi + ((size_t)b * 64 + c) * 1024 + mc * 64 + mm;
      *(float4*)&phi_s[c][mm]     = *(const float4*)&p[0];
      *(float4*)&phi_s[c][mm + 4] = *(const float4*)&p[4];
    }
    __syncthreads();
    const int ml = l16 * 4;
    float s0 = 0.f, s1 = 0.f, s2 = 0.f, s3 = 0.f;
#pragma unroll 16
    for (int c = 0; c < 64; ++c) {
      float a = th[c];
      float4 p4 = *(const float4*)&phi_s[c][ml];
      s0 += a * p4.x; s1 += a * p4.y; s2 += a * p4.z; s3 += a * p4.w;
    }
    *(float4*)&S_s[qA][mc * 64 + ml] = make_float4(s0, s1, s2, s3);
  }
  __syncthreads();

  // ---- softmax rows (16 threads per row, strided float4 walk) ----
  {
    float mx = -3.0e38f;
#pragma unroll
    for (int j = 0; j < 16; ++j) {
      float4 v = *(const float4*)&S_s[qA][l16 * 4 + j * 64];
      mx = fmaxf(mx, fmaxf(fmaxf(v.x, v.y), fmaxf(v.z, v.w)));
    }
    mx = fmaxf(mx, __shfl_xor(mx, 1));
    mx = fmaxf(mx, __shfl_xor(mx, 2));
    mx = fmaxf(mx, __shfl_xor(mx, 4));
    mx = fmaxf(mx, __shfl_xor(mx, 8));
    float sum = 0.f;
#pragma unroll
    for (int j = 0; j < 16; ++j) {
      float4 v = *(float4*)&S_s[qA][l16 * 4 + j * 64];
      v.x = __expf(v.x - mx); v.y = __expf(v.y - mx);
      v.z = __expf(v.z - mx); v.w = __expf(v.w - mx);
      sum += v.x + v.y + v.z + v.w;
      *(float4*)&S_s[qA][l16 * 4 + j * 64] = v;
    }
    sum += __shfl_xor(sum, 1);
    sum += __shfl_xor(sum, 2);
    sum += __shfl_xor(sum, 4);
    sum += __shfl_xor(sum, 8);
    float inv = 1.0f / sum;
#pragma unroll
    for (int j = 0; j < 16; ++j) {
      float4 v = *(float4*)&S_s[qA][l16 * 4 + j * 64];
      v.x *= inv; v.y *= inv; v.z *= inv; v.w *= inv;
      *(float4*)&S_s[qA][l16 * 4 + j * 64] = v;
    }
  }
  __syncthreads();

  // ---- PV: O[32q x 256c] ----
  {
    const int qq = t & 31, cb = (t >> 5) * 16;  // 16 c per thread
    float acc[16];
#pragma unroll
    for (int i = 0; i < 16; ++i) acc[i] = 0.f;
    const float* gb = g + (size_t)b * 1024 * 256 + cb;
    for (int m = 0; m < 1024; m += 4) {
      float4 s4 = *(const float4*)&S_s[qq][m];
      float sArr[4] = {s4.x, s4.y, s4.z, s4.w};
#pragma unroll
      for (int mi = 0; mi < 4; ++mi) {
        float s = sArr[mi];
        const float* gr = gb + (size_t)(m + mi) * 256;
#pragma unroll
        for (int jj = 0; jj < 4; ++jj) {
          float4 gv = *(const float4*)&gr[jj * 4];
          acc[jj * 4 + 0] += s * gv.x;
          acc[jj * 4 + 1] += s * gv.y;
          acc[jj * 4 + 2] += s * gv.z;
          acc[jj * 4 + 3] += s * gv.w;
        }
      }
    }
    float* op = O + ((size_t)b * 4096 + q0 + qq) * 256 + cb;
#pragma unroll
    for (int jj = 0; jj < 4; ++jj)
      *(float4*)&op[jj * 4] =
          make_float4(acc[jj * 4], acc[jj * 4 + 1], acc[jj * 4 + 2], acc[jj * 4 + 3]);
  }
}

// ---------------- final conv + residual ----------------
// out[b,o,n] = X[b,o,n] + sigma * (b_attn[o] + sum_c Wa[o,c] * O[b,n,c])
__global__ __launch_bounds__(256) void out_kernel(
    const float* __restrict__ X, const float* __restrict__ O,
    const float* __restrict__ Wa, const float* __restrict__ ba,
    const float* __restrict__ sigma, float* __restrict__ out) {
  const int b = blockIdx.z, mt = blockIdx.y, nt = blockIdx.x;
  const int m0 = mt * 128, n0 = nt * 128;
  __shared__ float As[16][132];
  __shared__ float Bs[16][132];
  const int t = threadIdx.x, tx = t & 15, ty = t >> 4;
  float acc[8][8];
#pragma unroll
  for (int i = 0; i < 8; ++i)
#pragma unroll
    for (int j = 0; j < 8; ++j) acc[i][j] = 0.f;
  const float* Ob = O + (size_t)b * 4096 * 256;

  for (int k0 = 0; k0 < 256; k0 += 16) {
#pragma unroll
    for (int p = 0; p < 2; ++p) {  // A = Wa[512,256]
      int e = p * 256 + t;
      int row = e >> 2, kq = e & 3;
      float4 a4 = *(const float4*)&Wa[(size_t)(m0 + row) * 256 + k0 + kq * 4];
      As[kq * 4 + 0][row] = a4.x;
      As[kq * 4 + 1][row] = a4.y;
      As[kq * 4 + 2][row] = a4.z;
      As[kq * 4 + 3][row] = a4.w;
    }
#pragma unroll
    for (int p = 0; p < 2; ++p) {  // B[k][n] = O[n][k] (transposed store)
      int e = p * 256 + t;
      int n = e >> 2, kq = e & 3;
      float4 b4 = *(const float4*)&Ob[(size_t)(n0 + n) * 256 + k0 + kq * 4];
      Bs[kq * 4 + 0][n] = b4.x;
      Bs[kq * 4 + 1][n] = b4.y;
      Bs[kq * 4 + 2][n] = b4.z;
      Bs[kq * 4 + 3][n] = b4.w;
    }
    __syncthreads();
#pragma unroll
    for (int kk = 0; kk < 16; ++kk) {
      float4 a0 = *(const float4*)&As[kk][ty * 8];
      float4 a1 = *(const float4*)&As[kk][ty * 8 + 4];
      float4 b0 = *(const float4*)&Bs[kk][tx * 4];
      float4 b1 = *(const float4*)&Bs[kk][tx * 4 + 64];
      float av[8] = {a0.x, a0.y, a0.z, a0.w, a1.x, a1.y, a1.z, a1.w};
      float bv[8] = {b0.x, b0.y, b0.z, b0.w, b1.x, b1.y, b1.z, b1.w};
#pragma unroll
      for (int i = 0; i < 8; ++i)
#pragma unroll
        for (int j = 0; j < 8; ++j) acc[i][j] += av[i] * bv[j];
    }
    __syncthreads();
  }

  const float sg = sigma[0];
#pragma unroll
  for (int i = 0; i < 8; ++i) {
    int o = m0 + ty * 8 + i;
    float bias = ba[o];
    const size_t rowoff = ((size_t)b * 512 + o) * 4096 + n0;
    float4 x0 = *(const float4*)&X[rowoff + tx * 4];
    float4 x1 = *(const float4*)&X[rowoff + 64 + tx * 4];
    float4 r0, r1;
    r0.x = x0.x + sg * (acc[i][0] + bias);
    r0.y = x0.y + sg * (acc[i][1] + bias);
    r0.z = x0.z + sg * (acc[i][2] + bias);
    r0.w = x0.w + sg * (acc[i][3] + bias);
    r1.x = x1.x + sg * (acc[i][4] + bias);
    r1.y = x1.y + sg * (acc[i][5] + bias);
    r1.z = x1.z + sg * (acc[i][6] + bias);
    r1.w = x1.w + sg * (acc[i][7] + bias);
    *(float4*)&out[rowoff + tx * 4] = r0;
    *(float4*)&out[rowoff + 64 + tx * 4] = r1;
  }
}

extern "C" void kernel_launch(void* const* d_in, const int* in_sizes, int n_in,
                              void* d_out, int out_size, void* d_ws, size_t ws_size,
                              hipStream_t stream) {
  (void)in_sizes; (void)n_in; (void)out_size; (void)ws_size;
  const float* X  = (const float*)d_in[0];
  const float* wt = (const float*)d_in[1];
  const float* bt = (const float*)d_in[2];
  const float* wp = (const float*)d_in[3];
  const float* bp = (const float*)d_in[4];
  const float* wg = (const float*)d_in[5];
  const float* bg = (const float*)d_in[6];
  const float* wa = (const float*)d_in[7];
  const float* ba = (const float*)d_in[8];
  const float* sg = (const float*)d_in[9];
  float* out = (float*)d_out;
  float* ws = (float*)d_ws;

  // workspace layout (floats):
  float* Wcat  = ws;              // 384*512      = 196608
  float* bcat  = ws + 196608;     // 384
  float* theta = ws + 196992;     // 16*64*4096   = 4194304
  float* phi_p = ws + 4391296;    // 16*64*1024   = 1048576
  float* g_p   = ws + 5439872;    // 16*1024*256  = 4194304
  float* O     = ws + 9634176;    // 16*4096*256  = 16777216
  // total 26411392 floats = 105.6 MiB

  pack_kernel<<<dim3(768), dim3(256), 0, stream>>>(wt, bt, wp, bp, wg, bg, Wcat, bcat);
  conv_pool_kernel<<<dim3(32, 3, 16), dim3(256), 0, stream>>>(X, Wcat, bcat, theta, phi_p, g_p);
  attn_kernel<<<dim3(128, 16), dim3(512), 0, stream>>>(theta, phi_p, g_p, O);
  out_kernel<<<dim3(32, 4, 16), dim3(256), 0, stream>>>(X, O, wa, ba, sg, out);
}

// Round 2
// 904.556 us; speedup vs baseline: 3.5578x; 3.5578x over previous
//
#include <hip/hip_runtime.h>
#include <cstdint>
#include <cstddef>

// B=16, C=512, H=W=64, HW=4096, C8=64, C2=256, M(keys)=1024

typedef float f32x4 __attribute__((ext_vector_type(4)));
typedef short bf16x8 __attribute__((ext_vector_type(8)));

static __device__ __forceinline__ float max4f(float a, float b, float c, float d) {
  return fmaxf(fmaxf(a, b), fmaxf(c, d));
}

static __device__ __forceinline__ unsigned short f2bf(float f) {
  unsigned int u = __float_as_uint(f);
  unsigned int r = u + 0x7fffu + ((u >> 16) & 1u);  // RNE
  return (unsigned short)(r >> 16);
}

// ---------------- pack weights: Wcat [384][512], bcat[384] ----------------
__global__ __launch_bounds__(256) void pack_kernel(
    const float* __restrict__ wt, const float* __restrict__ bt,
    const float* __restrict__ wp, const float* __restrict__ bp,
    const float* __restrict__ wg, const float* __restrict__ bg,
    float* __restrict__ Wcat, float* __restrict__ bcat) {
  int i = blockIdx.x * 256 + threadIdx.x;
  if (i < 384 * 512) {
    int o = i >> 9, k = i & 511;
    float v;
    if (o < 64)       v = wt[o * 512 + k];
    else if (o < 128) v = wp[(o - 64) * 512 + k];
    else              v = wg[(o - 128) * 512 + k];
    Wcat[i] = v;
  }
  if (i < 384) {
    float v;
    if (i < 64)       v = bt[i];
    else if (i < 128) v = bp[i - 64];
    else              v = bg[i - 128];
    bcat[i] = v;
  }
}

// ---------------- conv GEMM + fused maxpool epilogue (bf16 outputs) ----------------
// Y[384,4096] = Wcat @ X_b
//   theta rows 0..63   -> theta_t [B][4096 q][64 c]  bf16  (A-frag friendly)
//   phi   rows 64..127 -> pooled  phi_t [B][1024 m][64 c]  bf16 (B-frag friendly)
//   g     rows 128..383-> pooled  g_t  [B][256 c][1024 m]  bf16 (B-frag friendly)
__global__ __launch_bounds__(256) void conv_pool_kernel(
    const float* __restrict__ X, const float* __restrict__ Wcat,
    const float* __restrict__ bcat,
    unsigned short* __restrict__ theta_t, unsigned short* __restrict__ phi_t,
    unsigned short* __restrict__ g_t) {
  const int b = blockIdx.z, mt = blockIdx.y, nt = blockIdx.x;
  const int m0 = mt * 128, n0 = nt * 128;
  __shared__ union {
    struct { float As[16][132]; float Bs[16][132]; } ab;
    float cs[64][132];
  } sm;
  const int t = threadIdx.x, tx = t & 15, ty = t >> 4;
  float acc[8][8];
#pragma unroll
  for (int i = 0; i < 8; ++i)
#pragma unroll
    for (int j = 0; j < 8; ++j) acc[i][j] = 0.f;
  const float* Xb = X + (size_t)b * 512 * 4096;

  for (int k0 = 0; k0 < 512; k0 += 16) {
#pragma unroll
    for (int p = 0; p < 2; ++p) {  // A tile (transposed store)
      int e = p * 256 + t;
      int row = e >> 2, kq = e & 3;
      float4 a4 = *(const float4*)&Wcat[(size_t)(m0 + row) * 512 + k0 + kq * 4];
      sm.ab.As[kq * 4 + 0][row] = a4.x;
      sm.ab.As[kq * 4 + 1][row] = a4.y;
      sm.ab.As[kq * 4 + 2][row] = a4.z;
      sm.ab.As[kq * 4 + 3][row] = a4.w;
    }
#pragma unroll
    for (int p = 0; p < 2; ++p) {  // B tile (direct)
      int e = p * 256 + t;
      int kr = e >> 5, nq = e & 31;
      *(float4*)&sm.ab.Bs[kr][nq * 4] =
          *(const float4*)&Xb[(size_t)(k0 + kr) * 4096 + n0 + nq * 4];
    }
    __syncthreads();
#pragma unroll
    for (int kk = 0; kk < 16; ++kk) {
      float4 a0 = *(const float4*)&sm.ab.As[kk][ty * 8];
      float4 a1 = *(const float4*)&sm.ab.As[kk][ty * 8 + 4];
      float4 b0 = *(const float4*)&sm.ab.Bs[kk][tx * 4];
      float4 b1 = *(const float4*)&sm.ab.Bs[kk][tx * 4 + 64];
      float av[8] = {a0.x, a0.y, a0.z, a0.w, a1.x, a1.y, a1.z, a1.w};
      float bv[8] = {b0.x, b0.y, b0.z, b0.w, b1.x, b1.y, b1.z, b1.w};
#pragma unroll
      for (int i = 0; i < 8; ++i)
#pragma unroll
        for (int j = 0; j < 8; ++j) acc[i][j] += av[i] * bv[j];
    }
    __syncthreads();
  }

  // epilogue in two stripes of 64 rows, via LDS C-tile
  for (int s = 0; s < 2; ++s) {
    if ((ty >> 3) == s) {
      int tyl = ty & 7;
#pragma unroll
      for (int i = 0; i < 8; ++i) {
        int r = tyl * 8 + i;
        float bias = bcat[m0 + s * 64 + r];
#pragma unroll
        for (int j = 0; j < 4; ++j) {
          sm.cs[r][tx * 4 + j]      = acc[i][j]     + bias;
          sm.cs[r][64 + tx * 4 + j] = acc[i][j + 4] + bias;
        }
      }
    }
    __syncthreads();
    const int o0 = m0 + s * 64;
    if (o0 < 64) {  // theta: -> [B][4096][64] bf16
      int col = t >> 1, half = t & 1;
      unsigned short vals[32];
#pragma unroll
      for (int i = 0; i < 32; ++i) vals[i] = f2bf(sm.cs[half * 32 + i][col]);
      unsigned short* dst = theta_t + ((size_t)b * 4096 + n0 + col) * 64 + half * 32;
#pragma unroll
      for (int j = 0; j < 4; ++j) ((uint4*)dst)[j] = ((const uint4*)vals)[j];
    } else if (o0 < 128) {  // phi: 2x2 pool -> [B][1024][64] bf16
      int px = t >> 3, ch0 = (t & 7) * 8;
      unsigned short v[8];
#pragma unroll
      for (int j = 0; j < 8; ++j) {
        int ch = ch0 + j;
        v[j] = f2bf(max4f(sm.cs[ch][2 * px], sm.cs[ch][2 * px + 1],
                          sm.cs[ch][64 + 2 * px], sm.cs[ch][64 + 2 * px + 1]));
      }
      *(uint4*)&phi_t[((size_t)b * 1024 + nt * 32 + px) * 64 + ch0] = *(const uint4*)v;
    } else {  // g: 2x2 pool -> [B][256][1024] bf16 (c-major)
      int ch = t >> 2, px0 = (t & 3) * 8;
      int gc = o0 - 128 + ch;
      unsigned short v[8];
#pragma unroll
      for (int j = 0; j < 8; ++j) {
        int px = px0 + j;
        v[j] = f2bf(max4f(sm.cs[ch][2 * px], sm.cs[ch][2 * px + 1],
                          sm.cs[ch][64 + 2 * px], sm.cs[ch][64 + 2 * px + 1]));
      }
      *(uint4*)&g_t[((size_t)b * 256 + gc) * 1024 + nt * 32 + px0] = *(const uint4*)v;
    }
    __syncthreads();
  }
}

// ---------------- fused MFMA attention ----------------
// block = 256 threads (4 waves), 32 queries. Wave w: QK over keys [256w,256w+256),
// softmax exact via cross-wave LDS stats, P -> bf16 LDS, PV over c-slice [64w,64w+64).
__global__ __launch_bounds__(256, 2) void attn_kernel(
    const unsigned short* __restrict__ theta, const unsigned short* __restrict__ phi,
    const unsigned short* __restrict__ g, float* __restrict__ O) {
  const int b = blockIdx.y, q0 = blockIdx.x * 32;
  __shared__ unsigned short S_s[32][1032];  // +16B pad: kills 16-way b128 conflict
  __shared__ float smax[4][32];
  __shared__ float ssum[4][32];
  const int t = threadIdx.x;
  const int w = t >> 6, lane = t & 63;
  const int l16 = lane & 15, quad = lane >> 4;
  const int m0w = w * 256;

  // ---- QK^T: S[32 q][256 m] per wave, in registers ----
  bf16x8 afrag[2][2];
#pragma unroll
  for (int qt = 0; qt < 2; ++qt)
#pragma unroll
    for (int kh = 0; kh < 2; ++kh)
      afrag[qt][kh] = *(const bf16x8*)&theta[((size_t)b * 4096 + q0 + qt * 16 + l16) * 64 +
                                             kh * 32 + quad * 8];

  f32x4 acc[2][16];
#pragma unroll
  for (int qt = 0; qt < 2; ++qt)
#pragma unroll
    for (int mt = 0; mt < 16; ++mt) acc[qt][mt] = (f32x4)(0.f);

  const unsigned short* phiB = phi + (size_t)b * 1024 * 64;
#pragma unroll
  for (int mt = 0; mt < 16; ++mt) {
    int m = m0w + mt * 16 + l16;
    bf16x8 b0 = *(const bf16x8*)&phiB[(size_t)m * 64 + quad * 8];
    bf16x8 b1 = *(const bf16x8*)&phiB[(size_t)m * 64 + 32 + quad * 8];
#pragma unroll
    for (int qt = 0; qt < 2; ++qt) {
      acc[qt][mt] = __builtin_amdgcn_mfma_f32_16x16x32_bf16(afrag[qt][0], b0, acc[qt][mt], 0, 0, 0);
      acc[qt][mt] = __builtin_amdgcn_mfma_f32_16x16x32_bf16(afrag[qt][1], b1, acc[qt][mt], 0, 0, 0);
    }
  }

  // ---- softmax (exact, fp32 stats) ----
  // lane holds S[q = qt*16 + quad*4 + reg][m = m0w + mt*16 + l16]
  float mx8[8];
#pragma unroll
  for (int r = 0; r < 8; ++r) {
    int qt = r >> 2, reg = r & 3;
    float m = acc[qt][0][reg];
#pragma unroll
    for (int mt = 1; mt < 16; ++mt) m = fmaxf(m, acc[qt][mt][reg]);
#pragma unroll
    for (int d = 1; d < 16; d <<= 1) m = fmaxf(m, __shfl_xor(m, d));
    mx8[r] = m;
  }
  if (l16 == 0) {
#pragma unroll
    for (int r = 0; r < 8; ++r) smax[w][(r >> 2) * 16 + quad * 4 + (r & 3)] = mx8[r];
  }
  __syncthreads();
  float gmx[8];
#pragma unroll
  for (int r = 0; r < 8; ++r) {
    int q = (r >> 2) * 16 + quad * 4 + (r & 3);
    gmx[r] = fmaxf(fmaxf(smax[0][q], smax[1][q]), fmaxf(smax[2][q], smax[3][q]));
  }
  float sum8[8];
#pragma unroll
  for (int r = 0; r < 8; ++r) sum8[r] = 0.f;
#pragma unroll
  for (int qt = 0; qt < 2; ++qt)
#pragma unroll
    for (int mt = 0; mt < 16; ++mt)
#pragma unroll
      for (int reg = 0; reg < 4; ++reg) {
        int r = qt * 4 + reg;
        float p = __expf(acc[qt][mt][reg] - gmx[r]);
        acc[qt][mt][reg] = p;
        sum8[r] += p;
      }
#pragma unroll
  for (int r = 0; r < 8; ++r) {
#pragma unroll
    for (int d = 1; d < 16; d <<= 1) sum8[r] += __shfl_xor(sum8[r], d);
  }
  if (l16 == 0) {
#pragma unroll
    for (int r = 0; r < 8; ++r) ssum[w][(r >> 2) * 16 + quad * 4 + (r & 3)] = sum8[r];
  }
  __syncthreads();
  float inv8[8];
#pragma unroll
  for (int r = 0; r < 8; ++r) {
    int q = (r >> 2) * 16 + quad * 4 + (r & 3);
    inv8[r] = 1.0f / (ssum[0][q] + ssum[1][q] + ssum[2][q] + ssum[3][q]);
  }
  // write P (bf16) to LDS
#pragma unroll
  for (int qt = 0; qt < 2; ++qt)
#pragma unroll
    for (int mt = 0; mt < 16; ++mt)
#pragma unroll
      for (int reg = 0; reg < 4; ++reg) {
        int q = qt * 16 + quad * 4 + reg;
        S_s[q][m0w + mt * 16 + l16] = f2bf(acc[qt][mt][reg] * inv8[qt * 4 + reg]);
      }
  __syncthreads();

  // ---- PV: O[32 q][64 c] per wave ----
  const int cbase = w * 64;
  f32x4 accO[2][4];
#pragma unroll
  for (int qt = 0; qt < 2; ++qt)
#pragma unroll
    for (int ct = 0; ct < 4; ++ct) accO[qt][ct] = (f32x4)(0.f);
  const unsigned short* gB = g + (size_t)b * 256 * 1024;
  for (int k0 = 0; k0 < 1024; k0 += 32) {
    bf16x8 a0 = *(const bf16x8*)&S_s[l16][k0 + quad * 8];
    bf16x8 a1 = *(const bf16x8*)&S_s[16 + l16][k0 + quad * 8];
#pragma unroll
    for (int ct = 0; ct < 4; ++ct) {
      bf16x8 bb = *(const bf16x8*)&gB[(size_t)(cbase + ct * 16 + l16) * 1024 + k0 + quad * 8];
      accO[0][ct] = __builtin_amdgcn_mfma_f32_16x16x32_bf16(a0, bb, accO[0][ct], 0, 0, 0);
      accO[1][ct] = __builtin_amdgcn_mfma_f32_16x16x32_bf16(a1, bb, accO[1][ct], 0, 0, 0);
    }
  }
  float* Ob = O + ((size_t)b * 4096 + q0) * 256;
#pragma unroll
  for (int qt = 0; qt < 2; ++qt)
#pragma unroll
    for (int ct = 0; ct < 4; ++ct)
#pragma unroll
      for (int reg = 0; reg < 4; ++reg)
        Ob[(size_t)(qt * 16 + quad * 4 + reg) * 256 + cbase + ct * 16 + l16] =
            accO[qt][ct][reg];
}

// ---------------- final conv + residual ----------------
__global__ __launch_bounds__(256) void out_kernel(
    const float* __restrict__ X, const float* __restrict__ O,
    const float* __restrict__ Wa, const float* __restrict__ ba,
    const float* __restrict__ sigma, float* __restrict__ out) {
  const int b = blockIdx.z, mt = blockIdx.y, nt = blockIdx.x;
  const int m0 = mt * 128, n0 = nt * 128;
  __shared__ float As[16][132];
  __shared__ float Bs[16][132];
  const int t = threadIdx.x, tx = t & 15, ty = t >> 4;
  float acc[8][8];
#pragma unroll
  for (int i = 0; i < 8; ++i)
#pragma unroll
    for (int j = 0; j < 8; ++j) acc[i][j] = 0.f;
  const float* Ob = O + (size_t)b * 4096 * 256;

  for (int k0 = 0; k0 < 256; k0 += 16) {
#pragma unroll
    for (int p = 0; p < 2; ++p) {  // A = Wa[512,256]
      int e = p * 256 + t;
      int row = e >> 2, kq = e & 3;
      float4 a4 = *(const float4*)&Wa[(size_t)(m0 + row) * 256 + k0 + kq * 4];
      As[kq * 4 + 0][row] = a4.x;
      As[kq * 4 + 1][row] = a4.y;
      As[kq * 4 + 2][row] = a4.z;
      As[kq * 4 + 3][row] = a4.w;
    }
#pragma unroll
    for (int p = 0; p < 2; ++p) {  // B[k][n] = O[n][k] (transposed store)
      int e = p * 256 + t;
      int n = e >> 2, kq = e & 3;
      float4 b4 = *(const float4*)&Ob[(size_t)(n0 + n) * 256 + k0 + kq * 4];
      Bs[kq * 4 + 0][n] = b4.x;
      Bs[kq * 4 + 1][n] = b4.y;
      Bs[kq * 4 + 2][n] = b4.z;
      Bs[kq * 4 + 3][n] = b4.w;
    }
    __syncthreads();
#pragma unroll
    for (int kk = 0; kk < 16; ++kk) {
      float4 a0 = *(const float4*)&As[kk][ty * 8];
      float4 a1 = *(const float4*)&As[kk][ty * 8 + 4];
      float4 b0 = *(const float4*)&Bs[kk][tx * 4];
      float4 b1 = *(const float4*)&Bs[kk][tx * 4 + 64];
      float av[8] = {a0.x, a0.y, a0.z, a0.w, a1.x, a1.y, a1.z, a1.w};
      float bv[8] = {b0.x, b0.y, b0.z, b0.w, b1.x, b1.y, b1.z, b1.w};
#pragma unroll
      for (int i = 0; i < 8; ++i)
#pragma unroll
        for (int j = 0; j < 8; ++j) acc[i][j] += av[i] * bv[j];
    }
    __syncthreads();
  }

  const float sg = sigma[0];
#pragma unroll
  for (int i = 0; i < 8; ++i) {
    int o = m0 + ty * 8 + i;
    float bias = ba[o];
    const size_t rowoff = ((size_t)b * 512 + o) * 4096 + n0;
    float4 x0 = *(const float4*)&X[rowoff + tx * 4];
    float4 x1 = *(const float4*)&X[rowoff + 64 + tx * 4];
    float4 r0, r1;
    r0.x = x0.x + sg * (acc[i][0] + bias);
    r0.y = x0.y + sg * (acc[i][1] + bias);
    r0.z = x0.z + sg * (acc[i][2] + bias);
    r0.w = x0.w + sg * (acc[i][3] + bias);
    r1.x = x1.x + sg * (acc[i][4] + bias);
    r1.y = x1.y + sg * (acc[i][5] + bias);
    r1.z = x1.z + sg * (acc[i][6] + bias);
    r1.w = x1.w + sg * (acc[i][7] + bias);
    *(float4*)&out[rowoff + tx * 4] = r0;
    *(float4*)&out[rowoff + 64 + tx * 4] = r1;
  }
}

extern "C" void kernel_launch(void* const* d_in, const int* in_sizes, int n_in,
                              void* d_out, int out_size, void* d_ws, size_t ws_size,
                              hipStream_t stream) {
  (void)in_sizes; (void)n_in; (void)out_size; (void)ws_size;
  const float* X  = (const float*)d_in[0];
  const float* wt = (const float*)d_in[1];
  const float* bt = (const float*)d_in[2];
  const float* wp = (const float*)d_in[3];
  const float* bp = (const float*)d_in[4];
  const float* wg = (const float*)d_in[5];
  const float* bg = (const float*)d_in[6];
  const float* wa = (const float*)d_in[7];
  const float* ba = (const float*)d_in[8];
  const float* sg = (const float*)d_in[9];
  float* out = (float*)d_out;
  char* base = (char*)d_ws;

  // workspace layout (bytes):
  float*          Wcat    = (float*)(base);                    // 786,432 B
  float*          bcat    = (float*)(base + 786432);           // 1,536 B
  unsigned short* theta_t = (unsigned short*)(base + (1u << 20));        // 8 MiB
  unsigned short* phi_t   = (unsigned short*)(base + (9u << 20));        // 2 MiB
  unsigned short* g_t     = (unsigned short*)(base + (11u << 20));       // 8 MiB
  float*          O       = (float*)(base + (19u << 20));                // 64 MiB
  // total 83 MiB (< 105.6 MiB used by the passing round-1 kernel)

  pack_kernel<<<dim3(768), dim3(256), 0, stream>>>(wt, bt, wp, bp, wg, bg, Wcat, bcat);
  conv_pool_kernel<<<dim3(32, 3, 16), dim3(256), 0, stream>>>(X, Wcat, bcat, theta_t, phi_t, g_t);
  attn_kernel<<<dim3(128, 16), dim3(256), 0, stream>>>(theta_t, phi_t, g_t, O);
  out_kernel<<<dim3(32, 4, 16), dim3(256), 0, stream>>>(X, O, wa, ba, sg, out);
}

// Round 3
// 607.249 us; speedup vs baseline: 5.2997x; 1.4896x over previous
//
#include <hip/hip_runtime.h>
#include <cstdint>
#include <cstddef>

// B=16, C=512, H=W=64, HW=4096, C8=64, C2=256, M(keys)=1024

typedef float f32x4 __attribute__((ext_vector_type(4)));
typedef short bf16x8 __attribute__((ext_vector_type(8)));

static __device__ __forceinline__ float max4f(float a, float b, float c, float d) {
  return fmaxf(fmaxf(a, b), fmaxf(c, d));
}

static __device__ __forceinline__ unsigned short f2bf(float f) {
  unsigned int u = __float_as_uint(f);
  unsigned int r = u + 0x7fffu + ((u >> 16) & 1u);  // RNE
  return (unsigned short)(r >> 16);
}

// ---------------- pack weights: Wcat_bf [384][512], bcat[384] fp32, Wa_bf [512][256] ----------------
__global__ __launch_bounds__(256) void pack_kernel(
    const float* __restrict__ wt, const float* __restrict__ bt,
    const float* __restrict__ wp, const float* __restrict__ bp,
    const float* __restrict__ wg, const float* __restrict__ bg,
    const float* __restrict__ wa,
    unsigned short* __restrict__ Wcat_bf, float* __restrict__ bcat,
    unsigned short* __restrict__ Wa_bf) {
  int i = blockIdx.x * 256 + threadIdx.x;
  if (i < 384 * 512) {
    int o = i >> 9, k = i & 511;
    float v;
    if (o < 64)       v = wt[o * 512 + k];
    else if (o < 128) v = wp[(o - 64) * 512 + k];
    else              v = wg[(o - 128) * 512 + k];
    Wcat_bf[i] = f2bf(v);
  }
  if (i < 512 * 256) Wa_bf[i] = f2bf(wa[i]);
  if (i < 384) {
    float v;
    if (i < 64)       v = bt[i];
    else if (i < 128) v = bp[i - 64];
    else              v = bg[i - 128];
    bcat[i] = v;
  }
}

// ---------------- transpose/convert: X fp32 [B][512][4096] -> Xbf_T bf16 [B][4096][512] ----------------
// block handles 64 n-positions x full K=512. LDS [64 n][516 k] bf16 (pad 4 -> odd word stride-ish).
__global__ __launch_bounds__(256) void transpose_kernel(
    const float* __restrict__ X, unsigned short* __restrict__ Xbf_T) {
  __shared__ unsigned short smT[64 * 516];
  const int b = blockIdx.y, n0 = blockIdx.x * 64;
  const int t = threadIdx.x;
  const float* Xb = X + (size_t)b * 512 * 4096;

  // phase 1: coalesced float4 reads, scattered bf16 LDS stores
  {
    const int nq = t & 15, kr = t >> 4;
#pragma unroll 4
    for (int it = 0; it < 32; ++it) {
      int k = it * 16 + kr;
      float4 v = *(const float4*)&Xb[(size_t)k * 4096 + n0 + nq * 4];
      smT[(nq * 4 + 0) * 516 + k] = f2bf(v.x);
      smT[(nq * 4 + 1) * 516 + k] = f2bf(v.y);
      smT[(nq * 4 + 2) * 516 + k] = f2bf(v.z);
      smT[(nq * 4 + 3) * 516 + k] = f2bf(v.w);
    }
  }
  __syncthreads();

  // phase 2: each store instruction writes one full output row (64 lanes x 16B = 1KB)
  {
    const int c = t & 63, w = t >> 6;
#pragma unroll 4
    for (int i = 0; i < 16; ++i) {
      int n = w + 4 * i;
      const unsigned short* src = &smT[n * 516 + c * 8];
      uint2 lo = *(const uint2*)&src[0];
      uint2 hi = *(const uint2*)&src[4];
      uint4 v; v.x = lo.x; v.y = lo.y; v.z = hi.x; v.w = hi.y;
      *(uint4*)&Xbf_T[((size_t)b * 4096 + n0 + n) * 512 + c * 8] = v;
    }
  }
}

// ---------------- conv GEMM (bf16 MFMA) + fused maxpool epilogue ----------------
// C[384 m][4096 n] = Wcat @ X ; block tile 128m x 128n, 4 waves 2x2, wave 64x64, K=512.
// Direct global bf16x8 fragment loads (both operands k-contiguous).
__global__ __launch_bounds__(256, 3) void conv_pool_kernel(
    const unsigned short* __restrict__ Xbf_T, const unsigned short* __restrict__ Wcat_bf,
    const float* __restrict__ bcat,
    unsigned short* __restrict__ theta_t, unsigned short* __restrict__ phi_t,
    unsigned short* __restrict__ g_t) {
  const int b = blockIdx.z, mt = blockIdx.y, nt = blockIdx.x;
  const int n0 = nt * 128;
  __shared__ float cs[64][132];
  const int t = threadIdx.x;
  const int wave = t >> 6, lane = t & 63;
  const int wm = wave >> 1, wn = wave & 1;
  const int l16 = lane & 15, quad = lane >> 4;

  const unsigned short* aptr =
      Wcat_bf + (size_t)(mt * 128 + wm * 64 + l16) * 512 + quad * 8;
  const unsigned short* bptr =
      Xbf_T + ((size_t)b * 4096 + n0 + wn * 64 + l16) * 512 + quad * 8;

  f32x4 acc[4][4];
#pragma unroll
  for (int i = 0; i < 4; ++i)
#pragma unroll
    for (int j = 0; j < 4; ++j) acc[i][j] = (f32x4)(0.f);

  for (int k0 = 0; k0 < 512; k0 += 32) {
    bf16x8 af[4], bfr[4];
#pragma unroll
    for (int am = 0; am < 4; ++am) af[am] = *(const bf16x8*)(aptr + (size_t)am * 16 * 512 + k0);
#pragma unroll
    for (int bn = 0; bn < 4; ++bn) bfr[bn] = *(const bf16x8*)(bptr + (size_t)bn * 16 * 512 + k0);
#pragma unroll
    for (int am = 0; am < 4; ++am)
#pragma unroll
      for (int bn = 0; bn < 4; ++bn)
        acc[am][bn] = __builtin_amdgcn_mfma_f32_16x16x32_bf16(af[am], bfr[bn], acc[am][bn], 0, 0, 0);
  }

  // epilogue: two 64-row stripes through LDS
  for (int s = 0; s < 2; ++s) {
    const int m0 = mt * 128 + s * 64;
    const float bias_base = 0.f; (void)bias_base;
    if (wm == s) {
#pragma unroll
      for (int am = 0; am < 4; ++am)
#pragma unroll
        for (int bn = 0; bn < 4; ++bn)
#pragma unroll
          for (int reg = 0; reg < 4; ++reg)
            cs[am * 16 + quad * 4 + reg][wn * 64 + bn * 16 + l16] =
                acc[am][bn][reg] + bcat[m0 + am * 16 + quad * 4 + reg];
    }
    __syncthreads();
    if (m0 < 64) {  // theta: -> [B][4096][64] bf16
      int col = t >> 1, half = t & 1;
      unsigned short vals[32];
#pragma unroll
      for (int i = 0; i < 32; ++i) vals[i] = f2bf(cs[half * 32 + i][col]);
      unsigned short* dst = theta_t + ((size_t)b * 4096 + n0 + col) * 64 + half * 32;
#pragma unroll
      for (int j = 0; j < 4; ++j) ((uint4*)dst)[j] = ((const uint4*)vals)[j];
    } else if (m0 < 128) {  // phi: 2x2 pool -> [B][1024][64] bf16
      int px = t >> 3, ch0 = (t & 7) * 8;
      unsigned short v[8];
#pragma unroll
      for (int j = 0; j < 8; ++j) {
        int ch = ch0 + j;
        v[j] = f2bf(max4f(cs[ch][2 * px], cs[ch][2 * px + 1],
                          cs[ch][64 + 2 * px], cs[ch][64 + 2 * px + 1]));
      }
      *(uint4*)&phi_t[((size_t)b * 1024 + nt * 32 + px) * 64 + ch0] = *(const uint4*)v;
    } else {  // g: 2x2 pool -> [B][256][1024] bf16 (c-major)
      int ch = t >> 2, px0 = (t & 3) * 8;
      int gc = m0 - 128 + ch;
      unsigned short v[8];
#pragma unroll
      for (int j = 0; j < 8; ++j) {
        int px = px0 + j;
        v[j] = f2bf(max4f(cs[ch][2 * px], cs[ch][2 * px + 1],
                          cs[ch][64 + 2 * px], cs[ch][64 + 2 * px + 1]));
      }
      *(uint4*)&g_t[((size_t)b * 256 + gc) * 1024 + nt * 32 + px0] = *(const uint4*)v;
    }
    __syncthreads();
  }
}

// ---------------- fused MFMA attention (bf16 O output) ----------------
__global__ __launch_bounds__(256, 2) void attn_kernel(
    const unsigned short* __restrict__ theta, const unsigned short* __restrict__ phi,
    const unsigned short* __restrict__ g, unsigned short* __restrict__ Obf) {
  const int b = blockIdx.y, q0 = blockIdx.x * 32;
  __shared__ unsigned short S_s[32][1032];
  __shared__ float smax[4][32];
  __shared__ float ssum[4][32];
  const int t = threadIdx.x;
  const int w = t >> 6, lane = t & 63;
  const int l16 = lane & 15, quad = lane >> 4;
  const int m0w = w * 256;

  bf16x8 afrag[2][2];
#pragma unroll
  for (int qt = 0; qt < 2; ++qt)
#pragma unroll
    for (int kh = 0; kh < 2; ++kh)
      afrag[qt][kh] = *(const bf16x8*)&theta[((size_t)b * 4096 + q0 + qt * 16 + l16) * 64 +
                                             kh * 32 + quad * 8];

  f32x4 acc[2][16];
#pragma unroll
  for (int qt = 0; qt < 2; ++qt)
#pragma unroll
    for (int mt = 0; mt < 16; ++mt) acc[qt][mt] = (f32x4)(0.f);

  const unsigned short* phiB = phi + (size_t)b * 1024 * 64;
#pragma unroll
  for (int mt = 0; mt < 16; ++mt) {
    int m = m0w + mt * 16 + l16;
    bf16x8 b0 = *(const bf16x8*)&phiB[(size_t)m * 64 + quad * 8];
    bf16x8 b1 = *(const bf16x8*)&phiB[(size_t)m * 64 + 32 + quad * 8];
#pragma unroll
    for (int qt = 0; qt < 2; ++qt) {
      acc[qt][mt] = __builtin_amdgcn_mfma_f32_16x16x32_bf16(afrag[qt][0], b0, acc[qt][mt], 0, 0, 0);
      acc[qt][mt] = __builtin_amdgcn_mfma_f32_16x16x32_bf16(afrag[qt][1], b1, acc[qt][mt], 0, 0, 0);
    }
  }

  float mx8[8];
#pragma unroll
  for (int r = 0; r < 8; ++r) {
    int qt = r >> 2, reg = r & 3;
    float m = acc[qt][0][reg];
#pragma unroll
    for (int mt = 1; mt < 16; ++mt) m = fmaxf(m, acc[qt][mt][reg]);
#pragma unroll
    for (int d = 1; d < 16; d <<= 1) m = fmaxf(m, __shfl_xor(m, d));
    mx8[r] = m;
  }
  if (l16 == 0) {
#pragma unroll
    for (int r = 0; r < 8; ++r) smax[w][(r >> 2) * 16 + quad * 4 + (r & 3)] = mx8[r];
  }
  __syncthreads();
  float gmx[8];
#pragma unroll
  for (int r = 0; r < 8; ++r) {
    int q = (r >> 2) * 16 + quad * 4 + (r & 3);
    gmx[r] = fmaxf(fmaxf(smax[0][q], smax[1][q]), fmaxf(smax[2][q], smax[3][q]));
  }
  float sum8[8];
#pragma unroll
  for (int r = 0; r < 8; ++r) sum8[r] = 0.f;
#pragma unroll
  for (int qt = 0; qt < 2; ++qt)
#pragma unroll
    for (int mt = 0; mt < 16; ++mt)
#pragma unroll
      for (int reg = 0; reg < 4; ++reg) {
        int r = qt * 4 + reg;
        float p = __expf(acc[qt][mt][reg] - gmx[r]);
        acc[qt][mt][reg] = p;
        sum8[r] += p;
      }
#pragma unroll
  for (int r = 0; r < 8; ++r) {
#pragma unroll
    for (int d = 1; d < 16; d <<= 1) sum8[r] += __shfl_xor(sum8[r], d);
  }
  if (l16 == 0) {
#pragma unroll
    for (int r = 0; r < 8; ++r) ssum[w][(r >> 2) * 16 + quad * 4 + (r & 3)] = sum8[r];
  }
  __syncthreads();
  float inv8[8];
#pragma unroll
  for (int r = 0; r < 8; ++r) {
    int q = (r >> 2) * 16 + quad * 4 + (r & 3);
    inv8[r] = 1.0f / (ssum[0][q] + ssum[1][q] + ssum[2][q] + ssum[3][q]);
  }
#pragma unroll
  for (int qt = 0; qt < 2; ++qt)
#pragma unroll
    for (int mt = 0; mt < 16; ++mt)
#pragma unroll
      for (int reg = 0; reg < 4; ++reg) {
        int q = qt * 16 + quad * 4 + reg;
        S_s[q][m0w + mt * 16 + l16] = f2bf(acc[qt][mt][reg] * inv8[qt * 4 + reg]);
      }
  __syncthreads();

  const int cbase = w * 64;
  f32x4 accO[2][4];
#pragma unroll
  for (int qt = 0; qt < 2; ++qt)
#pragma unroll
    for (int ct = 0; ct < 4; ++ct) accO[qt][ct] = (f32x4)(0.f);
  const unsigned short* gB = g + (size_t)b * 256 * 1024;
  for (int k0 = 0; k0 < 1024; k0 += 32) {
    bf16x8 a0 = *(const bf16x8*)&S_s[l16][k0 + quad * 8];
    bf16x8 a1 = *(const bf16x8*)&S_s[16 + l16][k0 + quad * 8];
#pragma unroll
    for (int ct = 0; ct < 4; ++ct) {
      bf16x8 bb = *(const bf16x8*)&gB[(size_t)(cbase + ct * 16 + l16) * 1024 + k0 + quad * 8];
      accO[0][ct] = __builtin_amdgcn_mfma_f32_16x16x32_bf16(a0, bb, accO[0][ct], 0, 0, 0);
      accO[1][ct] = __builtin_amdgcn_mfma_f32_16x16x32_bf16(a1, bb, accO[1][ct], 0, 0, 0);
    }
  }
  unsigned short* Ob = Obf + ((size_t)b * 4096 + q0) * 256;
#pragma unroll
  for (int qt = 0; qt < 2; ++qt)
#pragma unroll
    for (int ct = 0; ct < 4; ++ct)
#pragma unroll
      for (int reg = 0; reg < 4; ++reg)
        Ob[(size_t)(qt * 16 + quad * 4 + reg) * 256 + cbase + ct * 16 + l16] =
            f2bf(accO[qt][ct][reg]);
}

// ---------------- final conv (bf16 MFMA) + residual ----------------
// out[b,m,n] = X[b,m,n] + sigma * (ba[m] + sum_k Wa[m,k] * O[b,n,k])
__global__ __launch_bounds__(256, 3) void out_kernel(
    const float* __restrict__ X, const unsigned short* __restrict__ Obf,
    const unsigned short* __restrict__ Wa_bf, const float* __restrict__ ba,
    const float* __restrict__ sigma, float* __restrict__ out) {
  const int b = blockIdx.z, mt = blockIdx.y, nt = blockIdx.x;
  const int t = threadIdx.x;
  const int wave = t >> 6, lane = t & 63;
  const int wm = wave >> 1, wn = wave & 1;
  const int l16 = lane & 15, quad = lane >> 4;

  const unsigned short* aptr = Wa_bf + (size_t)(mt * 128 + wm * 64 + l16) * 256 + quad * 8;
  const unsigned short* bptr =
      Obf + ((size_t)b * 4096 + nt * 128 + wn * 64 + l16) * 256 + quad * 8;

  f32x4 acc[4][4];
#pragma unroll
  for (int i = 0; i < 4; ++i)
#pragma unroll
    for (int j = 0; j < 4; ++j) acc[i][j] = (f32x4)(0.f);

#pragma unroll
  for (int k0 = 0; k0 < 256; k0 += 32) {
    bf16x8 af[4], bfr[4];
#pragma unroll
    for (int am = 0; am < 4; ++am) af[am] = *(const bf16x8*)(aptr + (size_t)am * 16 * 256 + k0);
#pragma unroll
    for (int bn = 0; bn < 4; ++bn) bfr[bn] = *(const bf16x8*)(bptr + (size_t)bn * 16 * 256 + k0);
#pragma unroll
    for (int am = 0; am < 4; ++am)
#pragma unroll
      for (int bn = 0; bn < 4; ++bn)
        acc[am][bn] = __builtin_amdgcn_mfma_f32_16x16x32_bf16(af[am], bfr[bn], acc[am][bn], 0, 0, 0);
  }

  const float sg = sigma[0];
#pragma unroll
  for (int am = 0; am < 4; ++am) {
#pragma unroll
    for (int reg = 0; reg < 4; ++reg) {
      int m = mt * 128 + wm * 64 + am * 16 + quad * 4 + reg;
      float bias = ba[m];
      size_t rowoff = ((size_t)b * 512 + m) * 4096 + nt * 128 + wn * 64;
#pragma unroll
      for (int bn = 0; bn < 4; ++bn) {
        size_t idx = rowoff + bn * 16 + l16;
        out[idx] = X[idx] + sg * (acc[am][bn][reg] + bias);
      }
    }
  }
}

extern "C" void kernel_launch(void* const* d_in, const int* in_sizes, int n_in,
                              void* d_out, int out_size, void* d_ws, size_t ws_size,
                              hipStream_t stream) {
  (void)in_sizes; (void)n_in; (void)out_size; (void)ws_size;
  const float* X  = (const float*)d_in[0];
  const float* wt = (const float*)d_in[1];
  const float* bt = (const float*)d_in[2];
  const float* wp = (const float*)d_in[3];
  const float* bp = (const float*)d_in[4];
  const float* wg = (const float*)d_in[5];
  const float* bg = (const float*)d_in[6];
  const float* wa = (const float*)d_in[7];
  const float* ba = (const float*)d_in[8];
  const float* sg = (const float*)d_in[9];
  float* out = (float*)d_out;
  char* base = (char*)d_ws;

  // workspace layout (bytes):
  unsigned short* Wcat_bf = (unsigned short*)(base);                 // 384KB
  unsigned short* Wa_bf   = (unsigned short*)(base + 0x60000);       // 256KB
  float*          bcat    = (float*)(base + 0xA0000);                // 1.5KB
  unsigned short* theta_t = (unsigned short*)(base + (1u << 20));    // 8 MiB
  unsigned short* phi_t   = (unsigned short*)(base + (9u << 20));    // 2 MiB
  unsigned short* g_t     = (unsigned short*)(base + (11u << 20));   // 8 MiB
  unsigned short* Xbf_T   = (unsigned short*)(base + (19u << 20));   // 64 MiB
  unsigned short* Obf     = (unsigned short*)(base + (19u << 20));   // 32 MiB (aliases Xbf_T; disjoint lifetime)
  // total 83 MiB

  pack_kernel<<<dim3(768), dim3(256), 0, stream>>>(wt, bt, wp, bp, wg, bg, wa,
                                                   Wcat_bf, bcat, Wa_bf);
  transpose_kernel<<<dim3(64, 16), dim3(256), 0, stream>>>(X, Xbf_T);
  conv_pool_kernel<<<dim3(32, 3, 16), dim3(256), 0, stream>>>(Xbf_T, Wcat_bf, bcat,
                                                              theta_t, phi_t, g_t);
  attn_kernel<<<dim3(128, 16), dim3(256), 0, stream>>>(theta_t, phi_t, g_t, Obf);
  out_kernel<<<dim3(32, 4, 16), dim3(256), 0, stream>>>(X, Obf, Wa_bf, ba, sg, out);
}

// Round 4
// 573.942 us; speedup vs baseline: 5.6073x; 1.0580x over previous
//
#include <hip/hip_runtime.h>
#include <cstdint>
#include <cstddef>

// B=16, C=512, H=W=64, HW=4096, C8=64, C2=256, M(keys)=1024

typedef float f32x4 __attribute__((ext_vector_type(4)));
typedef short bf16x8 __attribute__((ext_vector_type(8)));

static __device__ __forceinline__ float max4f(float a, float b, float c, float d) {
  return fmaxf(fmaxf(a, b), fmaxf(c, d));
}

static __device__ __forceinline__ unsigned short f2bf(float f) {
  unsigned int u = __float_as_uint(f);
  unsigned int r = u + 0x7fffu + ((u >> 16) & 1u);  // RNE
  return (unsigned short)(r >> 16);
}

// async 16B/lane global->LDS copy; lds base must be wave-uniform, HW scatters lane*16
static __device__ __forceinline__ void async_ld16(void* lds, const void* g) {
  __builtin_amdgcn_global_load_lds(
      (const __attribute__((address_space(1))) unsigned int*)g,
      (__attribute__((address_space(3))) unsigned int*)lds, 16, 0, 0);
}

// ---------------- pack weights: Wcat_bf [384][512], bcat[384] fp32, Wa_bf [512][256] ----------------
__global__ __launch_bounds__(256) void pack_kernel(
    const float* __restrict__ wt, const float* __restrict__ bt,
    const float* __restrict__ wp, const float* __restrict__ bp,
    const float* __restrict__ wg, const float* __restrict__ bg,
    const float* __restrict__ wa,
    unsigned short* __restrict__ Wcat_bf, float* __restrict__ bcat,
    unsigned short* __restrict__ Wa_bf) {
  int i = blockIdx.x * 256 + threadIdx.x;
  if (i < 384 * 512) {
    int o = i >> 9, k = i & 511;
    float v;
    if (o < 64)       v = wt[o * 512 + k];
    else if (o < 128) v = wp[(o - 64) * 512 + k];
    else              v = wg[(o - 128) * 512 + k];
    Wcat_bf[i] = f2bf(v);
  }
  if (i < 512 * 256) Wa_bf[i] = f2bf(wa[i]);
  if (i < 384) {
    float v;
    if (i < 64)       v = bt[i];
    else if (i < 128) v = bp[i - 64];
    else              v = bg[i - 128];
    bcat[i] = v;
  }
}

// ---------------- transpose/convert: X fp32 [B][512][4096] -> Xbf_T bf16 [B][4096][512] ----------------
__global__ __launch_bounds__(256) void transpose_kernel(
    const float* __restrict__ X, unsigned short* __restrict__ Xbf_T) {
  __shared__ unsigned short smT[64 * 516];
  const int b = blockIdx.y, n0 = blockIdx.x * 64;
  const int t = threadIdx.x;
  const float* Xb = X + (size_t)b * 512 * 4096;

  {
    const int nq = t & 15, kr = t >> 4;
#pragma unroll 4
    for (int it = 0; it < 32; ++it) {
      int k = it * 16 + kr;
      float4 v = *(const float4*)&Xb[(size_t)k * 4096 + n0 + nq * 4];
      smT[(nq * 4 + 0) * 516 + k] = f2bf(v.x);
      smT[(nq * 4 + 1) * 516 + k] = f2bf(v.y);
      smT[(nq * 4 + 2) * 516 + k] = f2bf(v.z);
      smT[(nq * 4 + 3) * 516 + k] = f2bf(v.w);
    }
  }
  __syncthreads();
  {
    const int c = t & 63, w = t >> 6;
#pragma unroll 4
    for (int i = 0; i < 16; ++i) {
      int n = w + 4 * i;
      const unsigned short* src = &smT[n * 516 + c * 8];
      uint2 lo = *(const uint2*)&src[0];
      uint2 hi = *(const uint2*)&src[4];
      uint4 v; v.x = lo.x; v.y = lo.y; v.z = hi.x; v.w = hi.y;
      *(uint4*)&Xbf_T[((size_t)b * 4096 + n0 + n) * 512 + c * 8] = v;
    }
  }
}

// ---------------- conv GEMM (bf16 MFMA, LDS-staged) + fused maxpool epilogue ----------------
// C[384 m][4096 n] = Wcat @ X; tile 128x128, BK=32, single-buffer global_load_lds staging.
__global__ __launch_bounds__(256, 3) void conv_pool_kernel(
    const unsigned short* __restrict__ Xbf_T, const unsigned short* __restrict__ Wcat_bf,
    const float* __restrict__ bcat,
    unsigned short* __restrict__ theta_t, unsigned short* __restrict__ phi_t,
    unsigned short* __restrict__ g_t) {
  const int b = blockIdx.z, mt = blockIdx.y, nt = blockIdx.x;
  const int n0 = nt * 128;
  __shared__ union {
    struct { unsigned short A[128 * 32]; unsigned short B[128 * 32]; } st;  // 8KB + 8KB
    float cs[64][132];                                                      // 33.8KB
  } sm;
  const int t = threadIdx.x;
  const int wave = t >> 6, lane = t & 63;
  const int wm = wave >> 1, wn = wave & 1;
  const int l16 = lane & 15, quad = lane >> 4;
  const int srow = lane >> 2, skq = (lane & 3) * 8;

  const unsigned short* gA = Wcat_bf + (size_t)(mt * 128) * 512 + skq;
  const unsigned short* gB = Xbf_T + ((size_t)b * 4096 + n0) * 512 + skq;
  const int r0 = wave * 32;

  f32x4 acc[4][4];
#pragma unroll
  for (int i = 0; i < 4; ++i)
#pragma unroll
    for (int j = 0; j < 4; ++j) acc[i][j] = (f32x4)(0.f);

  const int abase = (wm * 64 + l16) * 32 + quad * 8;
  const int bbase = (wn * 64 + l16) * 32 + quad * 8;

  for (int k0 = 0; k0 < 512; k0 += 32) {
    __syncthreads();  // prior frag reads done before overwrite
    async_ld16(&sm.st.A[(r0) * 32],      gA + (size_t)(r0 + srow) * 512 + k0);
    async_ld16(&sm.st.A[(r0 + 16) * 32], gA + (size_t)(r0 + 16 + srow) * 512 + k0);
    async_ld16(&sm.st.B[(r0) * 32],      gB + (size_t)(r0 + srow) * 512 + k0);
    async_ld16(&sm.st.B[(r0 + 16) * 32], gB + (size_t)(r0 + 16 + srow) * 512 + k0);
    __syncthreads();  // vmcnt drain -> staged data visible
    bf16x8 af[4], bfr[4];
#pragma unroll
    for (int am = 0; am < 4; ++am) af[am] = *(const bf16x8*)&sm.st.A[abase + am * 16 * 32];
#pragma unroll
    for (int bn = 0; bn < 4; ++bn) bfr[bn] = *(const bf16x8*)&sm.st.B[bbase + bn * 16 * 32];
#pragma unroll
    for (int am = 0; am < 4; ++am)
#pragma unroll
      for (int bn = 0; bn < 4; ++bn)
        acc[am][bn] = __builtin_amdgcn_mfma_f32_16x16x32_bf16(af[am], bfr[bn], acc[am][bn], 0, 0, 0);
  }
  __syncthreads();  // staging buffers dead; cs reuse safe

  // epilogue: two 64-row stripes through LDS
  for (int s = 0; s < 2; ++s) {
    const int m0 = mt * 128 + s * 64;
    if (wm == s) {
#pragma unroll
      for (int am = 0; am < 4; ++am)
#pragma unroll
        for (int bn = 0; bn < 4; ++bn)
#pragma unroll
          for (int reg = 0; reg < 4; ++reg)
            sm.cs[am * 16 + quad * 4 + reg][wn * 64 + bn * 16 + l16] =
                acc[am][bn][reg] + bcat[m0 + am * 16 + quad * 4 + reg];
    }
    __syncthreads();
    if (m0 < 64) {  // theta: -> [B][4096][64] bf16
      int col = t >> 1, half = t & 1;
      unsigned short vals[32];
#pragma unroll
      for (int i = 0; i < 32; ++i) vals[i] = f2bf(sm.cs[half * 32 + i][col]);
      unsigned short* dst = theta_t + ((size_t)b * 4096 + n0 + col) * 64 + half * 32;
#pragma unroll
      for (int j = 0; j < 4; ++j) ((uint4*)dst)[j] = ((const uint4*)vals)[j];
    } else if (m0 < 128) {  // phi: 2x2 pool -> [B][1024][64] bf16
      int px = t >> 3, ch0 = (t & 7) * 8;
      unsigned short v[8];
#pragma unroll
      for (int j = 0; j < 8; ++j) {
        int ch = ch0 + j;
        v[j] = f2bf(max4f(sm.cs[ch][2 * px], sm.cs[ch][2 * px + 1],
                          sm.cs[ch][64 + 2 * px], sm.cs[ch][64 + 2 * px + 1]));
      }
      *(uint4*)&phi_t[((size_t)b * 1024 + nt * 32 + px) * 64 + ch0] = *(const uint4*)v;
    } else {  // g: 2x2 pool -> [B][256][1024] bf16 (c-major)
      int ch = t >> 2, px0 = (t & 3) * 8;
      int gc = m0 - 128 + ch;
      unsigned short v[8];
#pragma unroll
      for (int j = 0; j < 8; ++j) {
        int px = px0 + j;
        v[j] = f2bf(max4f(sm.cs[ch][2 * px], sm.cs[ch][2 * px + 1],
                          sm.cs[ch][64 + 2 * px], sm.cs[ch][64 + 2 * px + 1]));
      }
      *(uint4*)&g_t[((size_t)b * 256 + gc) * 1024 + nt * 32 + px0] = *(const uint4*)v;
    }
    __syncthreads();
  }
}

// ---------------- fused MFMA attention: 512 threads, 8 waves ----------------
// wave w: QK over keys [128w,128w+128) for 32 queries; single stats barrier;
// P (normalized) -> bf16 LDS; PV over c-slice [32w,32w+32) x all 1024 keys.
__global__ __launch_bounds__(512, 4) void attn_kernel(
    const unsigned short* __restrict__ theta, const unsigned short* __restrict__ phi,
    const unsigned short* __restrict__ g, unsigned short* __restrict__ Obf) {
  const int b = blockIdx.y, q0 = blockIdx.x * 32;
  __shared__ unsigned short S_s[32][1032];  // 66 KB
  __shared__ float2 sstat[32][8];           // (m_w, sum_w) per q-row per wave
  const int t = threadIdx.x;
  const int w = t >> 6, lane = t & 63;
  const int l16 = lane & 15, quad = lane >> 4;
  const int m0w = w * 128;

  // A-frags: theta[32 q][64 c]
  bf16x8 afrag[2][2];
#pragma unroll
  for (int qt = 0; qt < 2; ++qt)
#pragma unroll
    for (int kh = 0; kh < 2; ++kh)
      afrag[qt][kh] = *(const bf16x8*)&theta[((size_t)b * 4096 + q0 + qt * 16 + l16) * 64 +
                                             kh * 32 + quad * 8];

  // ---- QK^T: S[32 q][128 m] per wave ----
  f32x4 acc[2][8];
#pragma unroll
  for (int qt = 0; qt < 2; ++qt)
#pragma unroll
    for (int mt = 0; mt < 8; ++mt) acc[qt][mt] = (f32x4)(0.f);

  const unsigned short* phiB = phi + (size_t)b * 1024 * 64;
#pragma unroll
  for (int mt = 0; mt < 8; ++mt) {
    int m = m0w + mt * 16 + l16;
    bf16x8 b0 = *(const bf16x8*)&phiB[(size_t)m * 64 + quad * 8];
    bf16x8 b1 = *(const bf16x8*)&phiB[(size_t)m * 64 + 32 + quad * 8];
#pragma unroll
    for (int qt = 0; qt < 2; ++qt) {
      acc[qt][mt] = __builtin_amdgcn_mfma_f32_16x16x32_bf16(afrag[qt][0], b0, acc[qt][mt], 0, 0, 0);
      acc[qt][mt] = __builtin_amdgcn_mfma_f32_16x16x32_bf16(afrag[qt][1], b1, acc[qt][mt], 0, 0, 0);
    }
  }

  // ---- per-wave max & exp-sum (rows: q = qt*16 + quad*4 + reg) ----
  float mx8[8], sum8[8];
#pragma unroll
  for (int r = 0; r < 8; ++r) {
    int qt = r >> 2, reg = r & 3;
    float m = acc[qt][0][reg];
#pragma unroll
    for (int mt = 1; mt < 8; ++mt) m = fmaxf(m, acc[qt][mt][reg]);
#pragma unroll
    for (int d = 1; d < 16; d <<= 1) m = fmaxf(m, __shfl_xor(m, d));
    mx8[r] = m;
    sum8[r] = 0.f;
  }
#pragma unroll
  for (int qt = 0; qt < 2; ++qt)
#pragma unroll
    for (int mt = 0; mt < 8; ++mt)
#pragma unroll
      for (int reg = 0; reg < 4; ++reg) {
        int r = qt * 4 + reg;
        float p = __expf(acc[qt][mt][reg] - mx8[r]);
        acc[qt][mt][reg] = p;
        sum8[r] += p;
      }
#pragma unroll
  for (int r = 0; r < 8; ++r) {
#pragma unroll
    for (int d = 1; d < 16; d <<= 1) sum8[r] += __shfl_xor(sum8[r], d);
  }
  if (l16 == 0) {
#pragma unroll
    for (int r = 0; r < 8; ++r) {
      int q = (r >> 2) * 16 + quad * 4 + (r & 3);
      sstat[q][w] = make_float2(mx8[r], sum8[r]);
    }
  }
  __syncthreads();  // single stats barrier

  // ---- global stats + normalized P write ----
  float alpha[8];
#pragma unroll
  for (int r = 0; r < 8; ++r) {
    int q = (r >> 2) * 16 + quad * 4 + (r & 3);
    float2 st[8];
#pragma unroll
    for (int j = 0; j < 4; ++j) ((float4*)st)[j] = *(const float4*)&sstat[q][j * 2];
    float mg = st[0].x;
#pragma unroll
    for (int j = 1; j < 8; ++j) mg = fmaxf(mg, st[j].x);
    float sg = 0.f;
#pragma unroll
    for (int j = 0; j < 8; ++j) sg += st[j].y * __expf(st[j].x - mg);
    alpha[r] = __expf(mx8[r] - mg) / sg;
  }
#pragma unroll
  for (int qt = 0; qt < 2; ++qt)
#pragma unroll
    for (int mt = 0; mt < 8; ++mt)
#pragma unroll
      for (int reg = 0; reg < 4; ++reg) {
        int q = qt * 16 + quad * 4 + reg;
        S_s[q][m0w + mt * 16 + l16] = f2bf(acc[qt][mt][reg] * alpha[qt * 4 + reg]);
      }
  __syncthreads();

  // ---- PV: O[32 q][32 c] per wave over all 1024 keys ----
  const int cbase = w * 32;
  f32x4 accO[2][2];
#pragma unroll
  for (int qt = 0; qt < 2; ++qt)
#pragma unroll
    for (int ct = 0; ct < 2; ++ct) accO[qt][ct] = (f32x4)(0.f);
  const unsigned short* gB = g + (size_t)b * 256 * 1024;
  for (int k0 = 0; k0 < 1024; k0 += 32) {
    bf16x8 a0 = *(const bf16x8*)&S_s[l16][k0 + quad * 8];
    bf16x8 a1 = *(const bf16x8*)&S_s[16 + l16][k0 + quad * 8];
#pragma unroll
    for (int ct = 0; ct < 2; ++ct) {
      bf16x8 bb = *(const bf16x8*)&gB[(size_t)(cbase + ct * 16 + l16) * 1024 + k0 + quad * 8];
      accO[0][ct] = __builtin_amdgcn_mfma_f32_16x16x32_bf16(a0, bb, accO[0][ct], 0, 0, 0);
      accO[1][ct] = __builtin_amdgcn_mfma_f32_16x16x32_bf16(a1, bb, accO[1][ct], 0, 0, 0);
    }
  }
  unsigned short* Ob = Obf + ((size_t)b * 4096 + q0) * 256;
#pragma unroll
  for (int qt = 0; qt < 2; ++qt)
#pragma unroll
    for (int ct = 0; ct < 2; ++ct)
#pragma unroll
      for (int reg = 0; reg < 4; ++reg)
        Ob[(size_t)(qt * 16 + quad * 4 + reg) * 256 + cbase + ct * 16 + l16] =
            f2bf(accO[qt][ct][reg]);
}

// ---------------- final conv (bf16 MFMA, LDS-staged) + residual ----------------
__global__ __launch_bounds__(256, 3) void out_kernel(
    const float* __restrict__ X, const unsigned short* __restrict__ Obf,
    const unsigned short* __restrict__ Wa_bf, const float* __restrict__ ba,
    const float* __restrict__ sigma, float* __restrict__ out) {
  const int b = blockIdx.z, mt = blockIdx.y, nt = blockIdx.x;
  __shared__ struct { unsigned short A[128 * 32]; unsigned short B[128 * 32]; } sm;
  const int t = threadIdx.x;
  const int wave = t >> 6, lane = t & 63;
  const int wm = wave >> 1, wn = wave & 1;
  const int l16 = lane & 15, quad = lane >> 4;
  const int srow = lane >> 2, skq = (lane & 3) * 8;

  const unsigned short* gA = Wa_bf + (size_t)(mt * 128) * 256 + skq;
  const unsigned short* gB = Obf + ((size_t)b * 4096 + nt * 128) * 256 + skq;
  const int r0 = wave * 32;

  f32x4 acc[4][4];
#pragma unroll
  for (int i = 0; i < 4; ++i)
#pragma unroll
    for (int j = 0; j < 4; ++j) acc[i][j] = (f32x4)(0.f);

  const int abase = (wm * 64 + l16) * 32 + quad * 8;
  const int bbase = (wn * 64 + l16) * 32 + quad * 8;

  for (int k0 = 0; k0 < 256; k0 += 32) {
    __syncthreads();
    async_ld16(&sm.A[(r0) * 32],      gA + (size_t)(r0 + srow) * 256 + k0);
    async_ld16(&sm.A[(r0 + 16) * 32], gA + (size_t)(r0 + 16 + srow) * 256 + k0);
    async_ld16(&sm.B[(r0) * 32],      gB + (size_t)(r0 + srow) * 256 + k0);
    async_ld16(&sm.B[(r0 + 16) * 32], gB + (size_t)(r0 + 16 + srow) * 256 + k0);
    __syncthreads();
    bf16x8 af[4], bfr[4];
#pragma unroll
    for (int am = 0; am < 4; ++am) af[am] = *(const bf16x8*)&sm.A[abase + am * 16 * 32];
#pragma unroll
    for (int bn = 0; bn < 4; ++bn) bfr[bn] = *(const bf16x8*)&sm.B[bbase + bn * 16 * 32];
#pragma unroll
    for (int am = 0; am < 4; ++am)
#pragma unroll
      for (int bn = 0; bn < 4; ++bn)
        acc[am][bn] = __builtin_amdgcn_mfma_f32_16x16x32_bf16(af[am], bfr[bn], acc[am][bn], 0, 0, 0);
  }

  const float sg = sigma[0];
#pragma unroll
  for (int am = 0; am < 4; ++am) {
#pragma unroll
    for (int reg = 0; reg < 4; ++reg) {
      int m = mt * 128 + wm * 64 + am * 16 + quad * 4 + reg;
      float bias = ba[m];
      size_t rowoff = ((size_t)b * 512 + m) * 4096 + nt * 128 + wn * 64;
#pragma unroll
      for (int bn = 0; bn < 4; ++bn) {
        size_t idx = rowoff + bn * 16 + l16;
        out[idx] = X[idx] + sg * (acc[am][bn][reg] + bias);
      }
    }
  }
}

extern "C" void kernel_launch(void* const* d_in, const int* in_sizes, int n_in,
                              void* d_out, int out_size, void* d_ws, size_t ws_size,
                              hipStream_t stream) {
  (void)in_sizes; (void)n_in; (void)out_size; (void)ws_size;
  const float* X  = (const float*)d_in[0];
  const float* wt = (const float*)d_in[1];
  const float* bt = (const float*)d_in[2];
  const float* wp = (const float*)d_in[3];
  const float* bp = (const float*)d_in[4];
  const float* wg = (const float*)d_in[5];
  const float* bg = (const float*)d_in[6];
  const float* wa = (const float*)d_in[7];
  const float* ba = (const float*)d_in[8];
  const float* sg = (const float*)d_in[9];
  float* out = (float*)d_out;
  char* base = (char*)d_ws;

  unsigned short* Wcat_bf = (unsigned short*)(base);                 // 384KB
  unsigned short* Wa_bf   = (unsigned short*)(base + 0x60000);       // 256KB
  float*          bcat    = (float*)(base + 0xA0000);                // 1.5KB
  unsigned short* theta_t = (unsigned short*)(base + (1u << 20));    // 8 MiB
  unsigned short* phi_t   = (unsigned short*)(base + (9u << 20));    // 2 MiB
  unsigned short* g_t     = (unsigned short*)(base + (11u << 20));   // 8 MiB
  unsigned short* Xbf_T   = (unsigned short*)(base + (19u << 20));   // 64 MiB
  unsigned short* Obf     = (unsigned short*)(base + (19u << 20));   // 32 MiB (aliases Xbf_T; disjoint lifetime)

  pack_kernel<<<dim3(768), dim3(256), 0, stream>>>(wt, bt, wp, bp, wg, bg, wa,
                                                   Wcat_bf, bcat, Wa_bf);
  transpose_kernel<<<dim3(64, 16), dim3(256), 0, stream>>>(X, Xbf_T);
  conv_pool_kernel<<<dim3(32, 3, 16), dim3(256), 0, stream>>>(Xbf_T, Wcat_bf, bcat,
                                                              theta_t, phi_t, g_t);
  attn_kernel<<<dim3(128, 16), dim3(512), 0, stream>>>(theta_t, phi_t, g_t, Obf);
  out_kernel<<<dim3(32, 4, 16), dim3(256), 0, stream>>>(X, Obf, Wa_bf, ba, sg, out);
}